// Round 1
// baseline (288.878 us; speedup 1.0000x reference)
//
#include <hip/hip_runtime.h>
#include <cstdint>
#include <cstddef>

#define B_ 8
#define N_ 10000
#define C_ 64
#define DIM_ 256
#define E_ 160000
#define ROWS_ (B_ * N_)            // 80000
#define OUT_OFF_ ((size_t)B_ * N_ * C_)  // 5,120,000

typedef unsigned short u16;
typedef unsigned int u32;
typedef __attribute__((ext_vector_type(8))) short bf16x8;
typedef __attribute__((ext_vector_type(4))) float f32x4;

__device__ __forceinline__ u16 f2bf(float f) {
    unsigned int u = __float_as_uint(f);
    unsigned int r = u + 0x7FFF + ((u >> 16) & 1);  // RNE
    return (u16)(r >> 16);
}
__device__ __forceinline__ float bf2f(u32 h) {      // low 16 bits hold bf16
    return __uint_as_float(h << 16);
}
__device__ __forceinline__ unsigned int pack2(float a, float b) {
    return (unsigned int)f2bf(a) | ((unsigned int)f2bf(b) << 16);
}
__device__ __forceinline__ float swish_f(float v, float sp) {
    float e = __expf(-v * sp);
    float s = __builtin_amdgcn_rcpf(1.0f + e);
    return v * s * (1.0f / 1.1f);
}

#define MFMA16(a, b, c) __builtin_amdgcn_mfma_f32_16x16x32_bf16(a, b, c, 0, 0, 0)

// ---- graph preprocessing -------------------------------------------------

__global__ void k_deg(const int* __restrict__ dst, const float* __restrict__ ew,
                      float* __restrict__ deg, int* __restrict__ cnt) {
    int e = blockIdx.x * 256 + threadIdx.x;
    if (e < E_) {
        int d = dst[e];
        atomicAdd(&deg[d], ew[e]);
        atomicAdd(&cnt[d], 1);
    }
}

__global__ void k_dis(const float* __restrict__ deg, float* __restrict__ dis) {
    int n = blockIdx.x * 256 + threadIdx.x;
    if (n < N_) {
        float d = deg[n];
        dis[n] = d > 0.f ? rsqrtf(d) : 0.f;
    }
}

__global__ void k_scan(const int* __restrict__ cnt, int* __restrict__ offs,
                       int* __restrict__ cursor) {
    __shared__ int part[1024];
    int t = threadIdx.x;
    const int CH = 10;
    int base = t * CH;
    int s = 0;
    for (int i = 0; i < CH; i++) {
        int idx = base + i;
        if (idx < N_) s += cnt[idx];
    }
    part[t] = s;
    __syncthreads();
    for (int off = 1; off < 1024; off <<= 1) {
        int v = 0;
        if (t >= off) v = part[t - off];
        __syncthreads();
        if (t >= off) part[t] += v;
        __syncthreads();
    }
    int run = (t > 0) ? part[t - 1] : 0;
    for (int i = 0; i < CH; i++) {
        int idx = base + i;
        if (idx < N_) {
            offs[idx] = run;
            cursor[idx] = run;
            run += cnt[idx];
        }
    }
    if (t == 1023) offs[N_] = run;
}

__global__ void k_scatter(const int* __restrict__ src, const int* __restrict__ dst,
                          const float* __restrict__ ew, const float* __restrict__ dis,
                          int* __restrict__ cursor, int* __restrict__ ssrc,
                          float* __restrict__ sw) {
    int e = blockIdx.x * 256 + threadIdx.x;
    if (e < E_) {
        int sn = src[e], dn = dst[e];
        float w = -(dis[sn] * ew[e] * dis[dn]);
        int p = atomicAdd(&cursor[dn], 1);
        ssrc[p] = sn;
        sw[p] = w;
    }
}

// weight transpose to N-major bf16 + vectorized x cast
__global__ void k_prepw(const float* __restrict__ Wc, const float* __restrict__ W1,
                        const float* __restrict__ W2, const float* __restrict__ x,
                        u16* __restrict__ Wct, u16* __restrict__ W1t,
                        u16* __restrict__ W2t, u16* __restrict__ xbf) {
    int i = blockIdx.x * 256 + threadIdx.x;
    if (i < 49152) {
        int nr = i / 192, k = i % 192;
        Wct[i] = f2bf(Wc[k * 256 + nr]);
    } else if (i < 114688) {
        int j = i - 49152;
        int nr = j >> 8, k = j & 255;
        W1t[j] = f2bf(W1[k * 256 + nr]);
    } else if (i < 131072) {
        int j = i - 114688;
        int nr = j >> 8, k = j & 255;
        W2t[j] = f2bf(W2[k * 64 + nr]);
    } else {
        int j = i - 131072;
        if (j < (B_ * N_ * C_) / 4) {
            float4 v = ((const float4*)x)[j];
            uint2 pv = {pack2(v.x, v.y), pack2(v.z, v.w)};
            ((uint2*)xbf)[j] = pv;
        }
    }
}

// bf16 gather SpMM. One wave per (batch, node); XCD-batch swizzle (b = blk&7).
// mode==1: O = 2*sum - xin  (fused Tx2 computation)
__global__ __launch_bounds__(256) void k_prop(
        const u16* __restrict__ T, const int* __restrict__ offs,
        const int* __restrict__ ssrc, const float* __restrict__ sw,
        const u16* __restrict__ xin, u16* __restrict__ O, int mode) {
    int w = __builtin_amdgcn_readfirstlane(threadIdx.x >> 6);
    int lane = threadIdx.x & 63;
    int b = blockIdx.x & 7;
    int nb = blockIdx.x >> 3;
    int n = nb * 4 + w;
    const u16* Tb = T + (size_t)b * (N_ * C_);
    int s = offs[n], e = offs[n + 1];
    float sum = 0.f;
    int j = s;
    for (; j < e && (j & 3); ++j) sum += bf2f(Tb[(size_t)ssrc[j] * 64 + lane]) * sw[j];
    for (; j + 4 <= e; j += 4) {
        int4 idx = *(const int4*)&ssrc[j];
        float4 wv = *(const float4*)&sw[j];
        sum += bf2f(Tb[(size_t)idx.x * 64 + lane]) * wv.x
             + bf2f(Tb[(size_t)idx.y * 64 + lane]) * wv.y
             + bf2f(Tb[(size_t)idx.z * 64 + lane]) * wv.z
             + bf2f(Tb[(size_t)idx.w * 64 + lane]) * wv.w;
    }
    for (; j < e; ++j) sum += bf2f(Tb[(size_t)ssrc[j] * 64 + lane]) * sw[j];
    size_t g = ((size_t)b * N_ + n) * 64 + lane;
    float v = sum;
    if (mode == 1) v = 2.f * sum - bf2f(xin[g]);
    O[g] = f2bf(v);
}

// ---- fused cheb-einsum + MLP, bf16 MFMA, M=64 rows/block -----------------
// 512 threads (8 waves, 2 blocks/CU -> 16 waves/CU). Wave (wm, wn):
// wm = w>>2 owns rows wm*32..+32, wn = w&3 owns a 64-col slice (16 for GEMM3).
// Halved per-wave work doubles resident-wave latency hiding; LDS unchanged.
__global__ __launch_bounds__(512, 4) void k_fused(
        const float* __restrict__ x, const u16* __restrict__ xbf,
        const u16* __restrict__ Tx1, const u16* __restrict__ Tx2,
        const u16* __restrict__ Wct, const float* __restrict__ bc,
        const u16* __restrict__ W1t, const float* __restrict__ b1,
        const u16* __restrict__ W2t, const float* __restrict__ b2,
        const float* __restrict__ beta, float* __restrict__ out) {
    __shared__ u16 buf0[64 * 264];  // A0 (stride 200), later h2/A2 (stride 264)
    __shared__ u16 buf1[64 * 264];  // h/A1 (stride 264)
    int t = threadIdx.x;

    // stage A0 = [xbf | Tx1 | Tx2] bf16, row-major, K-stride 200
    {
        size_t base = (size_t)blockIdx.x * 1024;  // uint2 units (64 rows x 16)
        const uint2* xb = (const uint2*)xbf + base;
        const uint2* tb = (const uint2*)Tx1 + base;
        const uint2* pb = (const uint2*)Tx2 + base;
#pragma unroll
        for (int rep = 0; rep < 2; ++rep) {
            int p = t + rep * 512;
            int r = p >> 4, c4 = p & 15;
            *(uint2*)&buf0[r * 200 + c4 * 4] = xb[p];
            *(uint2*)&buf0[r * 200 + 64 + c4 * 4] = tb[p];
            *(uint2*)&buf0[r * 200 + 128 + c4 * 4] = pb[p];
        }
    }
    __syncthreads();

    float sp = logf(1.f + expf(beta[0]));
    int lane = t & 63, w = t >> 6;
    int wn = w & 3, wm = w >> 2;
    int m = lane & 15, quad = lane >> 4;
    int rbase = wm * 32;

    // ---- GEMM1: h = A0[64x192] @ Wc[192x256], +bc, swish -> buf1
    {
        f32x4 acc[2][4] = {};
        bf16x8 bcur[4], bnxt[4];
        const u16* Wp = Wct + (wn * 64 + m) * 192 + quad * 8;
#pragma unroll
        for (int nt = 0; nt < 4; ++nt) bcur[nt] = *(const bf16x8*)(Wp + nt * 16 * 192);
        for (int kc = 0; kc < 6; ++kc) {
            if (kc < 5) {
#pragma unroll
                for (int nt = 0; nt < 4; ++nt)
                    bnxt[nt] = *(const bf16x8*)(Wp + nt * 16 * 192 + (kc + 1) * 32);
            }
            int koff = kc * 32 + quad * 8;
            bf16x8 a0 = *(const bf16x8*)&buf0[(rbase + m) * 200 + koff];
            bf16x8 a1 = *(const bf16x8*)&buf0[(rbase + 16 + m) * 200 + koff];
#pragma unroll
            for (int nt = 0; nt < 4; ++nt) {
                acc[0][nt] = MFMA16(a0, bcur[nt], acc[0][nt]);
                acc[1][nt] = MFMA16(a1, bcur[nt], acc[1][nt]);
            }
#pragma unroll
            for (int nt = 0; nt < 4; ++nt) bcur[nt] = bnxt[nt];
        }
#pragma unroll
        for (int mt = 0; mt < 2; ++mt)
#pragma unroll
            for (int nt = 0; nt < 4; ++nt) {
                int col = wn * 64 + nt * 16 + m;
                float bcv = bc[col];
#pragma unroll
                for (int i = 0; i < 4; ++i) {
                    int row = rbase + mt * 16 + quad * 4 + i;
                    buf1[row * 264 + col] = f2bf(swish_f(acc[mt][nt][i] + bcv, sp));
                }
            }
    }
    __syncthreads();

    // ---- GEMM2: h2 = A1[64x256] @ W1[256x256], +b1, swish -> buf0
    // (no barrier before the epilogue: buf0's A0 is dead since the post-GEMM1
    //  barrier, and GEMM2's MFMA phase only reads buf1)
    {
        f32x4 acc[2][4] = {};
        bf16x8 bcur[4], bnxt[4];
        const u16* Wp = W1t + (wn * 64 + m) * 256 + quad * 8;
#pragma unroll
        for (int nt = 0; nt < 4; ++nt) bcur[nt] = *(const bf16x8*)(Wp + nt * 16 * 256);
        for (int kc = 0; kc < 8; ++kc) {
            if (kc < 7) {
#pragma unroll
                for (int nt = 0; nt < 4; ++nt)
                    bnxt[nt] = *(const bf16x8*)(Wp + nt * 16 * 256 + (kc + 1) * 32);
            }
            int koff = kc * 32 + quad * 8;
            bf16x8 a0 = *(const bf16x8*)&buf1[(rbase + m) * 264 + koff];
            bf16x8 a1 = *(const bf16x8*)&buf1[(rbase + 16 + m) * 264 + koff];
#pragma unroll
            for (int nt = 0; nt < 4; ++nt) {
                acc[0][nt] = MFMA16(a0, bcur[nt], acc[0][nt]);
                acc[1][nt] = MFMA16(a1, bcur[nt], acc[1][nt]);
            }
#pragma unroll
            for (int nt = 0; nt < 4; ++nt) bcur[nt] = bnxt[nt];
        }
#pragma unroll
        for (int mt = 0; mt < 2; ++mt)
#pragma unroll
            for (int nt = 0; nt < 4; ++nt) {
                int col = wn * 64 + nt * 16 + m;
                float b1v = b1[col];
#pragma unroll
                for (int i = 0; i < 4; ++i) {
                    int row = rbase + mt * 16 + quad * 4 + i;
                    buf0[row * 264 + col] = f2bf(swish_f(acc[mt][nt][i] + b1v, sp));
                }
            }
    }
    __syncthreads();

    // ---- GEMM3: Fx = A2[64x256] @ W2[256x64], +b2; out = Fx + x, Fx
    {
        f32x4 acc3[2] = {};
        bf16x8 bcur, bnxt;
        const u16* Wp = W2t + (wn * 16 + m) * 256 + quad * 8;
        bcur = *(const bf16x8*)Wp;
        for (int kc = 0; kc < 8; ++kc) {
            if (kc < 7) bnxt = *(const bf16x8*)(Wp + (kc + 1) * 32);
            int koff = kc * 32 + quad * 8;
            bf16x8 a0 = *(const bf16x8*)&buf0[(rbase + m) * 264 + koff];
            bf16x8 a1 = *(const bf16x8*)&buf0[(rbase + 16 + m) * 264 + koff];
            acc3[0] = MFMA16(a0, bcur, acc3[0]);
            acc3[1] = MFMA16(a1, bcur, acc3[1]);
            bcur = bnxt;
        }
        int col = wn * 16 + m;
        float b2v = b2[col];
#pragma unroll
        for (int mt = 0; mt < 2; ++mt)
#pragma unroll
            for (int i = 0; i < 4; ++i) {
                int row = rbase + mt * 16 + quad * 4 + i;
                size_t g = ((size_t)blockIdx.x * 64 + row) * 64 + col;
                float f = acc3[mt][i] + b2v;
                out[g] = f + x[g];
                out[OUT_OFF_ + g] = f;
            }
    }
}

extern "C" void kernel_launch(void* const* d_in, const int* in_sizes, int n_in,
                              void* d_out, int out_size, void* d_ws, size_t ws_size,
                              hipStream_t stream) {
    const float* x    = (const float*)d_in[0];
    const float* ew   = (const float*)d_in[1];
    const float* Wc   = (const float*)d_in[2];
    const float* bc   = (const float*)d_in[3];
    const float* W1   = (const float*)d_in[4];
    const float* b1   = (const float*)d_in[5];
    const float* W2   = (const float*)d_in[6];
    const float* b2   = (const float*)d_in[7];
    const float* beta = (const float*)d_in[8];
    const int*   ei   = (const int*)d_in[9];
    const int* src = ei;
    const int* dst = ei + E_;
    float* out = (float*)d_out;

    // workspace layout (float units)
    float* ws = (float*)d_ws;
    float* deg    = ws + 0;                 // N
    float* dis    = ws + 10000;             // N
    int*   cnt    = (int*)(ws + 20000);     // N
    int*   offs   = (int*)(ws + 30000);     // N+1 (pad to 10008)
    int*   cursor = (int*)(ws + 40008);     // N
    int*   ssrc   = (int*)(ws + 50008);     // E
    float* sw     = ws + 210008;            // E
    u16*   xbf    = (u16*)(ws + 370008);    // B*N*C u16
    u16*   Tx1    = (u16*)(ws + 2930008);   // B*N*C u16
    u16*   Tx2    = (u16*)(ws + 5490008);   // B*N*C u16
    u16*   Wct    = (u16*)(ws + 8050008);   // 49152 u16
    u16*   W1t    = (u16*)(ws + 8074584);   // 65536 u16
    u16*   W2t    = (u16*)(ws + 8107352);   // 16384 u16

    hipMemsetAsync(deg, 0, (size_t)N_ * sizeof(float), stream);
    hipMemsetAsync(cnt, 0, (size_t)N_ * sizeof(int), stream);

    k_deg<<<(E_ + 255) / 256, 256, 0, stream>>>(dst, ew, deg, cnt);
    k_dis<<<(N_ + 255) / 256, 256, 0, stream>>>(deg, dis);
    k_scan<<<1, 1024, 0, stream>>>(cnt, offs, cursor);
    k_scatter<<<(E_ + 255) / 256, 256, 0, stream>>>(src, dst, ew, dis, cursor, ssrc, sw);
    k_prepw<<<(131072 + (B_ * N_ * C_) / 4 + 255) / 256, 256, 0, stream>>>(
        Wc, W1, W2, x, Wct, W1t, W2t, xbf);
    k_prop<<<N_ / 4 * 8, 256, 0, stream>>>(xbf, offs, ssrc, sw, xbf, Tx1, 0);
    k_prop<<<N_ / 4 * 8, 256, 0, stream>>>(Tx1, offs, ssrc, sw, xbf, Tx2, 1);
    k_fused<<<ROWS_ / 64, 512, 0, stream>>>(x, xbf, Tx1, Tx2, Wct, bc, W1t, b1,
                                            W2t, b2, beta, out);
}

// Round 2
// 263.782 us; speedup vs baseline: 1.0951x; 1.0951x over previous
//
#include <hip/hip_runtime.h>
#include <cstdint>
#include <cstddef>

#define B_ 8
#define N_ 10000
#define C_ 64
#define DIM_ 256
#define E_ 160000
#define ROWS_ (B_ * N_)            // 80000
#define OUT_OFF_ ((size_t)B_ * N_ * C_)  // 5,120,000

typedef unsigned short u16;
typedef unsigned int u32;
typedef __attribute__((ext_vector_type(8))) short bf16x8;
typedef __attribute__((ext_vector_type(4))) float f32x4;

__device__ __forceinline__ u16 f2bf(float f) {
    unsigned int u = __float_as_uint(f);
    unsigned int r = u + 0x7FFF + ((u >> 16) & 1);  // RNE
    return (u16)(r >> 16);
}
__device__ __forceinline__ float bf2f(u32 h) {      // low 16 bits hold bf16
    return __uint_as_float(h << 16);
}
__device__ __forceinline__ unsigned int pack2(float a, float b) {
    return (unsigned int)f2bf(a) | ((unsigned int)f2bf(b) << 16);
}
__device__ __forceinline__ float swish_f(float v, float sp) {
    float e = __expf(-v * sp);
    float s = __builtin_amdgcn_rcpf(1.0f + e);
    return v * s * (1.0f / 1.1f);
}

#define MFMA16(a, b, c) __builtin_amdgcn_mfma_f32_16x16x32_bf16(a, b, c, 0, 0, 0)

// ---- graph preprocessing -------------------------------------------------

__global__ void k_deg(const int* __restrict__ dst, const float* __restrict__ ew,
                      float* __restrict__ deg, int* __restrict__ cnt) {
    int e = blockIdx.x * 256 + threadIdx.x;
    if (e < E_) {
        int d = dst[e];
        atomicAdd(&deg[d], ew[e]);
        atomicAdd(&cnt[d], 1);
    }
}

__global__ void k_dis(const float* __restrict__ deg, float* __restrict__ dis) {
    int n = blockIdx.x * 256 + threadIdx.x;
    if (n < N_) {
        float d = deg[n];
        dis[n] = d > 0.f ? rsqrtf(d) : 0.f;
    }
}

__global__ void k_scan(const int* __restrict__ cnt, int* __restrict__ offs,
                       int* __restrict__ cursor) {
    __shared__ int part[1024];
    int t = threadIdx.x;
    const int CH = 10;
    int base = t * CH;
    int s = 0;
    for (int i = 0; i < CH; i++) {
        int idx = base + i;
        if (idx < N_) s += cnt[idx];
    }
    part[t] = s;
    __syncthreads();
    for (int off = 1; off < 1024; off <<= 1) {
        int v = 0;
        if (t >= off) v = part[t - off];
        __syncthreads();
        if (t >= off) part[t] += v;
        __syncthreads();
    }
    int run = (t > 0) ? part[t - 1] : 0;
    for (int i = 0; i < CH; i++) {
        int idx = base + i;
        if (idx < N_) {
            offs[idx] = run;
            cursor[idx] = run;
            run += cnt[idx];
        }
    }
    if (t == 1023) offs[N_] = run;
}

__global__ void k_scatter(const int* __restrict__ src, const int* __restrict__ dst,
                          const float* __restrict__ ew, const float* __restrict__ dis,
                          int* __restrict__ cursor, int* __restrict__ ssrc,
                          float* __restrict__ sw) {
    int e = blockIdx.x * 256 + threadIdx.x;
    if (e < E_) {
        int sn = src[e], dn = dst[e];
        float w = -(dis[sn] * ew[e] * dis[dn]);
        int p = atomicAdd(&cursor[dn], 1);
        ssrc[p] = sn;
        sw[p] = w;
    }
}

// weight transpose to N-major bf16 + vectorized x cast
__global__ void k_prepw(const float* __restrict__ Wc, const float* __restrict__ W1,
                        const float* __restrict__ W2, const float* __restrict__ x,
                        u16* __restrict__ Wct, u16* __restrict__ W1t,
                        u16* __restrict__ W2t, u16* __restrict__ xbf) {
    int i = blockIdx.x * 256 + threadIdx.x;
    if (i < 49152) {
        int nr = i / 192, k = i % 192;
        Wct[i] = f2bf(Wc[k * 256 + nr]);
    } else if (i < 114688) {
        int j = i - 49152;
        int nr = j >> 8, k = j & 255;
        W1t[j] = f2bf(W1[k * 256 + nr]);
    } else if (i < 131072) {
        int j = i - 114688;
        int nr = j >> 8, k = j & 255;
        W2t[j] = f2bf(W2[k * 64 + nr]);
    } else {
        int j = i - 131072;
        if (j < (B_ * N_ * C_) / 4) {
            float4 v = ((const float4*)x)[j];
            uint2 pv = {pack2(v.x, v.y), pack2(v.z, v.w)};
            ((uint2*)xbf)[j] = pv;
        }
    }
}

// bf16 gather SpMM. One wave per (batch, node); XCD-batch swizzle (b = blk&7).
// mode==1: O = 2*sum - xin  (fused Tx2 computation)
__global__ __launch_bounds__(256) void k_prop(
        const u16* __restrict__ T, const int* __restrict__ offs,
        const int* __restrict__ ssrc, const float* __restrict__ sw,
        const u16* __restrict__ xin, u16* __restrict__ O, int mode) {
    int w = __builtin_amdgcn_readfirstlane(threadIdx.x >> 6);
    int lane = threadIdx.x & 63;
    int b = blockIdx.x & 7;
    int nb = blockIdx.x >> 3;
    int n = nb * 4 + w;
    const u16* Tb = T + (size_t)b * (N_ * C_);
    int s = offs[n], e = offs[n + 1];
    float sum = 0.f;
    int j = s;
    for (; j < e && (j & 3); ++j) sum += bf2f(Tb[(size_t)ssrc[j] * 64 + lane]) * sw[j];
    for (; j + 4 <= e; j += 4) {
        int4 idx = *(const int4*)&ssrc[j];
        float4 wv = *(const float4*)&sw[j];
        sum += bf2f(Tb[(size_t)idx.x * 64 + lane]) * wv.x
             + bf2f(Tb[(size_t)idx.y * 64 + lane]) * wv.y
             + bf2f(Tb[(size_t)idx.z * 64 + lane]) * wv.z
             + bf2f(Tb[(size_t)idx.w * 64 + lane]) * wv.w;
    }
    for (; j < e; ++j) sum += bf2f(Tb[(size_t)ssrc[j] * 64 + lane]) * sw[j];
    size_t g = ((size_t)b * N_ + n) * 64 + lane;
    float v = sum;
    if (mode == 1) v = 2.f * sum - bf2f(xin[g]);
    O[g] = f2bf(v);
}

// ---- fused cheb-einsum + MLP, bf16 MFMA, M=64 rows/block -----------------
// 256 threads (4 waves); wave w owns a 64-col slice (16-col for GEMM3).
// R2 change: B fragments pipelined 4 kc-iterations deep in registers and A
// LDS-reads double-buffered 1 kc ahead — per-kc exposed B-load latency
// (~200-400 cyc vs ~60 cyc of slack with 1-deep prefetch) was the theory for
// the phase-locked stall (occupancy-doubling in R1 was flat -> not TLP-bound).
// VGPRs are free: LDS 67.6KB caps at 2 blocks/CU regardless.
__global__ __launch_bounds__(256, 2) void k_fused(
        const float* __restrict__ x, const u16* __restrict__ xbf,
        const u16* __restrict__ Tx1, const u16* __restrict__ Tx2,
        const u16* __restrict__ Wct, const float* __restrict__ bc,
        const u16* __restrict__ W1t, const float* __restrict__ b1,
        const u16* __restrict__ W2t, const float* __restrict__ b2,
        const float* __restrict__ beta, float* __restrict__ out) {
    __shared__ u16 buf0[64 * 264];  // A0 (stride 200), later h2/A2 (stride 264)
    __shared__ u16 buf1[64 * 264];  // h/A1 (stride 264)
    int t = threadIdx.x;

    // stage A0 = [xbf | Tx1 | Tx2] bf16, row-major, K-stride 200
    {
        size_t base = (size_t)blockIdx.x * 1024;  // uint2 units (64 rows x 16)
        const uint2* xb = (const uint2*)xbf + base;
        const uint2* tb = (const uint2*)Tx1 + base;
        const uint2* pb = (const uint2*)Tx2 + base;
#pragma unroll
        for (int rep = 0; rep < 4; ++rep) {
            int p = t + rep * 256;
            int r = p >> 4, c4 = p & 15;
            *(uint2*)&buf0[r * 200 + c4 * 4] = xb[p];
            *(uint2*)&buf0[r * 200 + 64 + c4 * 4] = tb[p];
            *(uint2*)&buf0[r * 200 + 128 + c4 * 4] = pb[p];
        }
    }
    __syncthreads();

    float sp = logf(1.f + expf(beta[0]));
    int lane = t & 63, w = t >> 6;
    int m = lane & 15, quad = lane >> 4;
    int q8 = quad * 8;

    // ---- GEMM1: h = A0[64x192] @ Wc[192x256], +bc, swish -> buf1
    {
        f32x4 acc[4][4] = {};
        bf16x8 bfr[4][4];   // rolling 4-deep B pipeline
        bf16x8 afr[2][4];   // A double-buffer (LDS latency ~120cyc)
        const u16* Wp = Wct + (w * 64 + m) * 192 + q8;
#pragma unroll
        for (int d = 0; d < 4; ++d)
#pragma unroll
            for (int nt = 0; nt < 4; ++nt)
                bfr[d][nt] = *(const bf16x8*)(Wp + nt * 16 * 192 + d * 32);
#pragma unroll
        for (int r = 0; r < 4; ++r)
            afr[0][r] = *(const bf16x8*)&buf0[(r * 16 + m) * 200 + q8];
#pragma unroll
        for (int kc = 0; kc < 6; ++kc) {
            if (kc < 5) {
                int koff2 = (kc + 1) * 32 + q8;
#pragma unroll
                for (int r = 0; r < 4; ++r)
                    afr[(kc + 1) & 1][r] = *(const bf16x8*)&buf0[(r * 16 + m) * 200 + koff2];
            }
#pragma unroll
            for (int nt = 0; nt < 4; ++nt) {
                acc[0][nt] = MFMA16(afr[kc & 1][0], bfr[kc & 3][nt], acc[0][nt]);
                acc[1][nt] = MFMA16(afr[kc & 1][1], bfr[kc & 3][nt], acc[1][nt]);
                acc[2][nt] = MFMA16(afr[kc & 1][2], bfr[kc & 3][nt], acc[2][nt]);
                acc[3][nt] = MFMA16(afr[kc & 1][3], bfr[kc & 3][nt], acc[3][nt]);
            }
            if (kc + 4 < 6) {
#pragma unroll
                for (int nt = 0; nt < 4; ++nt)
                    bfr[kc & 3][nt] = *(const bf16x8*)(Wp + nt * 16 * 192 + (kc + 4) * 32);
            }
        }
#pragma unroll
        for (int mt = 0; mt < 4; ++mt)
#pragma unroll
            for (int nt = 0; nt < 4; ++nt) {
                int col = w * 64 + nt * 16 + m;
                float bcv = bc[col];
#pragma unroll
                for (int i = 0; i < 4; ++i) {
                    int row = mt * 16 + quad * 4 + i;
                    buf1[row * 264 + col] = f2bf(swish_f(acc[mt][nt][i] + bcv, sp));
                }
            }
    }
    __syncthreads();

    // ---- GEMM2: h2 = A1[64x256] @ W1[256x256], +b1, swish -> buf0
    // (no barrier before the epilogue: buf0's A0 is dead since the post-GEMM1
    //  barrier, and GEMM2's MFMA phase only reads buf1)
    {
        f32x4 acc[4][4] = {};
        bf16x8 bfr[4][4];
        bf16x8 afr[2][4];
        const u16* Wp = W1t + (w * 64 + m) * 256 + q8;
#pragma unroll
        for (int d = 0; d < 4; ++d)
#pragma unroll
            for (int nt = 0; nt < 4; ++nt)
                bfr[d][nt] = *(const bf16x8*)(Wp + nt * 16 * 256 + d * 32);
#pragma unroll
        for (int r = 0; r < 4; ++r)
            afr[0][r] = *(const bf16x8*)&buf1[(r * 16 + m) * 264 + q8];
#pragma unroll
        for (int kc = 0; kc < 8; ++kc) {
            if (kc < 7) {
                int koff2 = (kc + 1) * 32 + q8;
#pragma unroll
                for (int r = 0; r < 4; ++r)
                    afr[(kc + 1) & 1][r] = *(const bf16x8*)&buf1[(r * 16 + m) * 264 + koff2];
            }
#pragma unroll
            for (int nt = 0; nt < 4; ++nt) {
                acc[0][nt] = MFMA16(afr[kc & 1][0], bfr[kc & 3][nt], acc[0][nt]);
                acc[1][nt] = MFMA16(afr[kc & 1][1], bfr[kc & 3][nt], acc[1][nt]);
                acc[2][nt] = MFMA16(afr[kc & 1][2], bfr[kc & 3][nt], acc[2][nt]);
                acc[3][nt] = MFMA16(afr[kc & 1][3], bfr[kc & 3][nt], acc[3][nt]);
            }
            if (kc + 4 < 8) {
#pragma unroll
                for (int nt = 0; nt < 4; ++nt)
                    bfr[kc & 3][nt] = *(const bf16x8*)(Wp + nt * 16 * 256 + (kc + 4) * 32);
            }
        }
#pragma unroll
        for (int mt = 0; mt < 4; ++mt)
#pragma unroll
            for (int nt = 0; nt < 4; ++nt) {
                int col = w * 64 + nt * 16 + m;
                float b1v = b1[col];
#pragma unroll
                for (int i = 0; i < 4; ++i) {
                    int row = mt * 16 + quad * 4 + i;
                    buf0[row * 264 + col] = f2bf(swish_f(acc[mt][nt][i] + b1v, sp));
                }
            }
    }
    __syncthreads();

    // ---- GEMM3: Fx = A2[64x256] @ W2[256x64], +b2; out = Fx + x, Fx
    {
        f32x4 acc3[4] = {};
        bf16x8 bfr[8];      // whole B panel preloaded (8 x 16B = 32 VGPR)
        bf16x8 afr[2][4];
        const u16* Wp = W2t + (w * 16 + m) * 256 + q8;
#pragma unroll
        for (int d = 0; d < 8; ++d) bfr[d] = *(const bf16x8*)(Wp + d * 32);
#pragma unroll
        for (int r = 0; r < 4; ++r)
            afr[0][r] = *(const bf16x8*)&buf0[(r * 16 + m) * 264 + q8];
#pragma unroll
        for (int kc = 0; kc < 8; ++kc) {
            if (kc < 7) {
                int koff2 = (kc + 1) * 32 + q8;
#pragma unroll
                for (int r = 0; r < 4; ++r)
                    afr[(kc + 1) & 1][r] = *(const bf16x8*)&buf0[(r * 16 + m) * 264 + koff2];
            }
            acc3[0] = MFMA16(afr[kc & 1][0], bfr[kc], acc3[0]);
            acc3[1] = MFMA16(afr[kc & 1][1], bfr[kc], acc3[1]);
            acc3[2] = MFMA16(afr[kc & 1][2], bfr[kc], acc3[2]);
            acc3[3] = MFMA16(afr[kc & 1][3], bfr[kc], acc3[3]);
        }
        int col = w * 16 + m;
        float b2v = b2[col];
#pragma unroll
        for (int mt = 0; mt < 4; ++mt)
#pragma unroll
            for (int i = 0; i < 4; ++i) {
                int row = mt * 16 + quad * 4 + i;
                size_t g = ((size_t)blockIdx.x * 64 + row) * 64 + col;
                float f = acc3[mt][i] + b2v;
                out[g] = f + x[g];
                out[OUT_OFF_ + g] = f;
            }
    }
}

extern "C" void kernel_launch(void* const* d_in, const int* in_sizes, int n_in,
                              void* d_out, int out_size, void* d_ws, size_t ws_size,
                              hipStream_t stream) {
    const float* x    = (const float*)d_in[0];
    const float* ew   = (const float*)d_in[1];
    const float* Wc   = (const float*)d_in[2];
    const float* bc   = (const float*)d_in[3];
    const float* W1   = (const float*)d_in[4];
    const float* b1   = (const float*)d_in[5];
    const float* W2   = (const float*)d_in[6];
    const float* b2   = (const float*)d_in[7];
    const float* beta = (const float*)d_in[8];
    const int*   ei   = (const int*)d_in[9];
    const int* src = ei;
    const int* dst = ei + E_;
    float* out = (float*)d_out;

    // workspace layout (float units)
    float* ws = (float*)d_ws;
    float* deg    = ws + 0;                 // N
    float* dis    = ws + 10000;             // N
    int*   cnt    = (int*)(ws + 20000);     // N
    int*   offs   = (int*)(ws + 30000);     // N+1 (pad to 10008)
    int*   cursor = (int*)(ws + 40008);     // N
    int*   ssrc   = (int*)(ws + 50008);     // E
    float* sw     = ws + 210008;            // E
    u16*   xbf    = (u16*)(ws + 370008);    // B*N*C u16
    u16*   Tx1    = (u16*)(ws + 2930008);   // B*N*C u16
    u16*   Tx2    = (u16*)(ws + 5490008);   // B*N*C u16
    u16*   Wct    = (u16*)(ws + 8050008);   // 49152 u16
    u16*   W1t    = (u16*)(ws + 8074584);   // 65536 u16
    u16*   W2t    = (u16*)(ws + 8107352);   // 16384 u16

    hipMemsetAsync(deg, 0, (size_t)N_ * sizeof(float), stream);
    hipMemsetAsync(cnt, 0, (size_t)N_ * sizeof(int), stream);

    k_deg<<<(E_ + 255) / 256, 256, 0, stream>>>(dst, ew, deg, cnt);
    k_dis<<<(N_ + 255) / 256, 256, 0, stream>>>(deg, dis);
    k_scan<<<1, 1024, 0, stream>>>(cnt, offs, cursor);
    k_scatter<<<(E_ + 255) / 256, 256, 0, stream>>>(src, dst, ew, dis, cursor, ssrc, sw);
    k_prepw<<<(131072 + (B_ * N_ * C_) / 4 + 255) / 256, 256, 0, stream>>>(
        Wc, W1, W2, x, Wct, W1t, W2t, xbf);
    k_prop<<<N_ / 4 * 8, 256, 0, stream>>>(xbf, offs, ssrc, sw, xbf, Tx1, 0);
    k_prop<<<N_ / 4 * 8, 256, 0, stream>>>(Tx1, offs, ssrc, sw, xbf, Tx2, 1);
    k_fused<<<ROWS_ / 64, 256, 0, stream>>>(x, xbf, Tx1, Tx2, Wct, bc, W1t, b1,
                                            W2t, b2, beta, out);
}